// Round 3
// baseline (306.428 us; speedup 1.0000x reference)
//
#include <hip/hip_runtime.h>

// Problem: preds (N=8,S=6,C=4,H=512,W=512) fp32, targets (8,6,512,512) int32.
// out = (1/N) * sum [logsumexp_c(preds) - preds[target]]   (scalar)
//
// R1: 12288 same-address atomicAdds serialized (168 us flat).
// R2: two-stage reduction -> 310 us (harness fixed overhead ~210 us).
// R3: batched loads @1024 blocks -> neutral (~101 us chain).
// R4: fused last-block epilogue -> VGPR 124, occ 18%, latency-bound. REGRESSED.
// R5: 1 quad/thread @12288 blocks, 16 VGPR -> 298 us total, ~88 us chain. BEST.
// R6: 2 quads/thread batched -> 302.5. Plateau ~3 TB/s across all structures.
// R7: R5 + NONTEMPORAL loads -> 280.1 us (~70 us chain, ~3.9 TB/s read).
// R8: persistent + 2-deep reg pipeline, launch_bounds(256,8) -> VGPR 32 cap,
//     compiler spilled pipeline (WRITE_SIZE 147 MB scratch). 374 us.
// R9: R8 with bound relaxed -> pipeline in regs, 283.7 us ~= R7. CONCLUSION:
//     read BW caps at ~3.9 TB/s across fire-and-die TLP, batched, and
//     persistent+ILP structures; VALUBusy ~10%. => per-CU outstanding-miss
//     cap on the VGPR-return load path (~85 lines x 64B / ~900cy = 6 B/cyc/CU).
// R10: THIS. Route reads through the OTHER hardware path: global_load_lds
//     (async DMA direct to LDS, no VGPR writeback, no per-lane miss entry).
//     Persistent 1024 blocks (4/CU), double-buffered 20 KiB LDS stages
//     (4 planes x 4KiB + targets 4KiB), 12 iters, compute 1 quad/thread
//     from LDS. Single variable changed: the load path.

#define HW      (512 * 512)
#define QUADS   (HW / 4)              // 65536 float4 groups per channel plane
#define NS      48                    // N*S
#define NQUAD   (NS * QUADS)          // 3,145,728 total quads
#define TPB     256
#define PBLK    1024                  // 4 blocks/CU (LDS-limited), persistent
#define ITERS   (NQUAD / (PBLK * TPB))   // 12 sweeps
#define INV_N   0.125f

#define BUF_FLOATS 5120               // 20 KiB per buffer: 4x4KiB preds + 4KiB tgt

typedef float vf4 __attribute__((ext_vector_type(4)));
typedef int   vi4 __attribute__((ext_vector_type(4)));

__device__ __forceinline__ float nll_one(float a, float b, float c, float d, int t) {
    float m = fmaxf(fmaxf(a, b), fmaxf(c, d));
    float s = __expf(a - m) + __expf(b - m) + __expf(c - m) + __expf(d - m);
    float lse = m + __logf(s);
    float xt = (t == 0) ? a : ((t == 1) ? b : ((t == 2) ? c : d));
    return lse - xt;
}

__device__ __forceinline__ float quad_nll(vf4 x0, vf4 x1, vf4 x2, vf4 x3, vi4 t) {
    return nll_one(x0.x, x1.x, x2.x, x3.x, t.x)
         + nll_one(x0.y, x1.y, x2.y, x3.y, t.y)
         + nll_one(x0.z, x1.z, x2.z, x3.z, t.z)
         + nll_one(x0.w, x1.w, x2.w, x3.w, t.w);
}

// 16B/lane global -> LDS DMA. LDS dest is wave-uniform base + lane*16 (linear).
static __device__ __forceinline__ void gld16(const void* g, void* l) {
    __builtin_amdgcn_global_load_lds(
        (const __attribute__((address_space(1))) unsigned int*)g,
        (__attribute__((address_space(3))) unsigned int*)l,
        16, 0, 0);
}

__global__ __launch_bounds__(TPB) void ce_partial(const float* __restrict__ preds,
                                                  const int* __restrict__ targets,
                                                  float* __restrict__ part) {
    __shared__ float S[2 * BUF_FLOATS];

    const int t    = threadIdx.x;
    const int lane = t & 63;
    const int wave = t >> 6;

    const vf4* __restrict__ p4 = (const vf4*)preds;
    const vi4* __restrict__ t4 = (const vi4*)targets;

    float lsum = 0.0f;

    // stage block-iteration 'it' into LDS buffer 'bb'
    auto stage = [&](int bb, int it) {
        const int g0 = (it * PBLK + (int)blockIdx.x) * TPB;  // first quad of tile
        const int ns = g0 >> 16;                             // tile never crosses ns
        const int q0 = g0 & (QUADS - 1);
        const int qq = q0 + wave * 64 + lane;                // this lane's quad
        float* dst = &S[bb * BUF_FLOATS + wave * 256];       // wave-uniform base
        #pragma unroll
        for (int c = 0; c < 4; ++c)
            gld16(p4 + (size_t)(ns * 4 + c) * QUADS + qq, dst + c * 1024);
        gld16(t4 + (size_t)ns * QUADS + qq, dst + 4096);
    };

    stage(0, 0);

    for (int it = 0; it < ITERS; ++it) {
        const int bb = it & 1;
        if (it + 1 < ITERS) stage(bb ^ 1, it + 1);  // async DMA into other buffer
        __syncthreads();                            // drains vmcnt: buf[bb] ready

        const float* B = &S[bb * BUF_FLOATS];
        vf4 x0 = ((const vf4*)(B))[t];
        vf4 x1 = ((const vf4*)(B + 1024))[t];
        vf4 x2 = ((const vf4*)(B + 2048))[t];
        vf4 x3 = ((const vf4*)(B + 3072))[t];
        vi4 tt = ((const vi4*)(B + 4096))[t];
        lsum += quad_nll(x0, x1, x2, x3, tt);

        __syncthreads();                            // buf[bb] reads done before reuse
    }

    // ---- block reduction ----
    #pragma unroll
    for (int off = 32; off > 0; off >>= 1)
        lsum += __shfl_down(lsum, off, 64);

    __shared__ float wsum[4];
    if (lane == 0) wsum[wave] = lsum;
    __syncthreads();
    if (t == 0)
        part[blockIdx.x] = (wsum[0] + wsum[1] + wsum[2] + wsum[3]) * INV_N;
}

__global__ __launch_bounds__(256) void ce_final(const float* __restrict__ part,
                                                float* __restrict__ out) {
    float lsum = 0.0f;
    #pragma unroll
    for (int i = 0; i < PBLK / 256; ++i)              // 4 iterations
        lsum += part[i * 256 + threadIdx.x];

    #pragma unroll
    for (int off = 32; off > 0; off >>= 1)
        lsum += __shfl_down(lsum, off, 64);

    __shared__ float wsum[4];
    const int lane = threadIdx.x & 63;
    const int wave = threadIdx.x >> 6;
    if (lane == 0) wsum[wave] = lsum;
    __syncthreads();
    if (threadIdx.x == 0)
        out[0] = wsum[0] + wsum[1] + wsum[2] + wsum[3];
}

extern "C" void kernel_launch(void* const* d_in, const int* in_sizes, int n_in,
                              void* d_out, int out_size, void* d_ws, size_t ws_size,
                              hipStream_t stream) {
    const float* preds   = (const float*)d_in[0];
    const int*   targets = (const int*)d_in[1];
    float*       part    = (float*)d_ws;     // PBLK floats = 4 KiB scratch
    float*       out     = (float*)d_out;

    ce_partial<<<PBLK, TPB, 0, stream>>>(preds, targets, part);
    ce_final<<<1, 256, 0, stream>>>(part, out);
}

// Round 4
// 291.694 us; speedup vs baseline: 1.0505x; 1.0505x over previous
//
#include <hip/hip_runtime.h>

// Problem: preds (N=8,S=6,C=4,H=512,W=512) fp32, targets (8,6,512,512) int32.
// out = (1/N) * sum [logsumexp_c(preds) - preds[target]]   (scalar)
//
// R1: 12288 same-address atomicAdds serialized (168 us flat).
// R2: two-stage reduction -> 310 us (harness fixed overhead ~210 us).
// R3: batched loads @1024 blocks -> neutral (~101 us chain).
// R4: fused last-block epilogue -> VGPR 124, occ 18%, latency-bound. REGRESSED.
// R5: 1 quad/thread @12288 blocks, 16 VGPR -> 298 us total, ~88 us chain. BEST.
// R6: 2 quads/thread batched -> 302.5. Plateau ~3 TB/s across all structures.
// R7: R5 + NONTEMPORAL loads -> 280.1 us (~70 us chain, ~3.9 TB/s read).
// R8: persistent + 2-deep reg pipeline, bounds(256,8) -> spilled. 374 us.
// R9: R8 relaxed -> real reg pipeline, 283.7 ~= R7. Read BW caps ~3.9 TB/s
//     across ALL VGPR-return structures (TLP, ILP, persistent). Concurrency
//     wall: ~90 64B lines/CU in flight at ~375ns => per-CU or shared cap?
// R10: all-DMA (global_load_lds) w/ double-buffer, but __syncthreads drains
//     vmcnt(0) including next tile's prefetch -> serialized latency. 306 us.
//     Confounded; did not answer the tracker question.
// R11: THIS. Dual-path hybrid in R5/R7 fire-and-die shape: planes 0,1 via
//     nt VGPR loads; planes 2,3 + targets via global_load_lds (no VGPR
//     writeback). One barrier per block (drain needed exactly once);
//     cross-block TLP provides overlap. If VGPR-return and LDS-DMA have
//     separate in-flight pools -> ~6.5 TB/s ceiling; if shared -> no change
//     and the cap is above the CU (declare roofline).

#define HW      (512 * 512)
#define QUADS   (HW / 4)              // 65536 float4 groups per channel plane
#define NS      48                    // N*S
#define NQUAD   (NS * QUADS)          // 3,145,728 total quads
#define TPB     256
#define NBLK    (NQUAD / TPB)         // 12288 blocks, 1 quad per thread
#define INV_N   0.125f

typedef float vf4 __attribute__((ext_vector_type(4)));
typedef int   vi4 __attribute__((ext_vector_type(4)));

__device__ __forceinline__ float nll_one(float a, float b, float c, float d, int t) {
    float m = fmaxf(fmaxf(a, b), fmaxf(c, d));
    float s = __expf(a - m) + __expf(b - m) + __expf(c - m) + __expf(d - m);
    float lse = m + __logf(s);
    float xt = (t == 0) ? a : ((t == 1) ? b : ((t == 2) ? c : d));
    return lse - xt;
}

// 16B/lane global->LDS DMA. Global addr is per-lane; LDS dest is wave-uniform
// base, HW writes lane l at dest + l*16 (linear, no padding allowed).
static __device__ __forceinline__ void gld16(const void* g, void* l) {
    __builtin_amdgcn_global_load_lds(
        (const __attribute__((address_space(1))) unsigned int*)g,
        (__attribute__((address_space(3))) unsigned int*)l,
        16, 0, 0);
}

__global__ __launch_bounds__(TPB) void ce_partial(const float* __restrict__ preds,
                                                  const int* __restrict__ targets,
                                                  float* __restrict__ part) {
    // 12 KiB: plane2 [1024 floats], plane3 [1024], targets [1024]
    __shared__ float S[3 * 1024];

    const int t    = threadIdx.x;
    const int lane = t & 63;
    const int wave = t >> 6;

    const int g  = blockIdx.x * TPB + t;   // global quad index
    const int ns = g >> 16;
    const int q  = g & (QUADS - 1);

    const vf4* __restrict__ p4 = (const vf4*)preds;
    const vi4* __restrict__ t4 = (const vi4*)targets;
    const int base = (ns << 2) * QUADS + q;

    // ---- DMA path: planes 2,3 + targets -> LDS (issued first) ----
    float* dst2 = &S[0]    + wave * 256;   // wave-uniform base, 1 KiB per wave
    float* dst3 = &S[1024] + wave * 256;
    float* dstT = &S[2048] + wave * 256;
    gld16(p4 + base + 2 * QUADS, dst2);
    gld16(p4 + base + 3 * QUADS, dst3);
    gld16(t4 + (size_t)ns * QUADS + q, dstT);

    // ---- VGPR path: planes 0,1 (nontemporal) ----
    vf4 x0 = __builtin_nontemporal_load(p4 + base);
    vf4 x1 = __builtin_nontemporal_load(p4 + base + QUADS);

    __syncthreads();   // drains vmcnt: DMA landed, x0/x1 resident

    vf4 x2 = ((const vf4*)(&S[0]))[t];
    vf4 x3 = ((const vf4*)(&S[1024]))[t];
    vi4 tt = ((const vi4*)(&S[2048]))[t];

    float lsum = nll_one(x0.x, x1.x, x2.x, x3.x, tt.x)
               + nll_one(x0.y, x1.y, x2.y, x3.y, tt.y)
               + nll_one(x0.z, x1.z, x2.z, x3.z, tt.z)
               + nll_one(x0.w, x1.w, x2.w, x3.w, tt.w);

    // ---- wave-64 reduction ----
    #pragma unroll
    for (int off = 32; off > 0; off >>= 1)
        lsum += __shfl_down(lsum, off, 64);

    __shared__ float wsum[4];
    if (lane == 0) wsum[wave] = lsum;
    __syncthreads();
    if (t == 0)
        part[blockIdx.x] = (wsum[0] + wsum[1] + wsum[2] + wsum[3]) * INV_N;
}

__global__ __launch_bounds__(256) void ce_final(const float* __restrict__ part,
                                                float* __restrict__ out) {
    float lsum = 0.0f;
    #pragma unroll
    for (int i = 0; i < NBLK / 256; ++i)          // 48 iterations
        lsum += part[i * 256 + threadIdx.x];

    #pragma unroll
    for (int off = 32; off > 0; off >>= 1)
        lsum += __shfl_down(lsum, off, 64);

    __shared__ float wsum[4];
    const int lane = threadIdx.x & 63;
    const int wave = threadIdx.x >> 6;
    if (lane == 0) wsum[wave] = lsum;
    __syncthreads();
    if (threadIdx.x == 0)
        out[0] = wsum[0] + wsum[1] + wsum[2] + wsum[3];
}

extern "C" void kernel_launch(void* const* d_in, const int* in_sizes, int n_in,
                              void* d_out, int out_size, void* d_ws, size_t ws_size,
                              hipStream_t stream) {
    const float* preds   = (const float*)d_in[0];
    const int*   targets = (const int*)d_in[1];
    float*       part    = (float*)d_ws;     // NBLK floats = 48 KiB scratch
    float*       out     = (float*)d_out;

    ce_partial<<<NBLK, TPB, 0, stream>>>(preds, targets, part);
    ce_final<<<1, 256, 0, stream>>>(part, out);
}